// Round 8
// baseline (2201.181 us; speedup 1.0000x reference)
//
#include <hip/hip_runtime.h>
#include <hip/hip_bf16.h>

#define NN 100000
#define NE 1000000
#define DD 128
#define RR 8
#define KCAT 1152               // 9*128 (8 relations + root)
#define NBLK 6250               // NN/16 exactly
#define ZROW NN                 // zero row index (fits 17 bits)
// LDS f32 layout: chunk = 8 f32 + 4 pad (stride 12), slice = 16 chunks (192),
// row = 9 slices + 4 pad (1732). 16 rows = 110,848 B.
#define CH_STRIDE 12
#define SL_STRIDE 192
#define ROW_STRIDE 1732

typedef short bf16x8 __attribute__((ext_vector_type(8)));
typedef float f32x4 __attribute__((ext_vector_type(4)));

__device__ __forceinline__ unsigned short f2bf(float f) {
    union { float f; unsigned int u; } c; c.f = f;
    unsigned int u = c.u;
    u += 0x7fffu + ((u >> 16) & 1u);    // round-to-nearest-even
    return (unsigned short)(u >> 16);
}

// fp32 -> bf16, 4 elems/thread
__global__ __launch_bounds__(256) void cvt_x_k(const float* __restrict__ in,
                                               unsigned short* __restrict__ out,
                                               int n4) {
    int i = blockIdx.x * 256 + threadIdx.x;
    if (i >= n4) return;
    float4 v = reinterpret_cast<const float4*>(in)[i];
    ushort4 o;
    o.x = f2bf(v.x); o.y = f2bf(v.y); o.z = f2bf(v.z); o.w = f2bf(v.w);
    reinterpret_cast<ushort4*>(out)[i] = o;
}

// Build Wcat[e][m*128+d] = W[m][d][e] (m<8) / root[d][e] (m==8), bf16, both layers.
__global__ __launch_bounds__(256) void cvt_w_k(const float* __restrict__ W1,
                                               const float* __restrict__ r1,
                                               const float* __restrict__ W2,
                                               const float* __restrict__ r2,
                                               unsigned short* __restrict__ wc1,
                                               unsigned short* __restrict__ wc2) {
    int idx = blockIdx.x * 256 + threadIdx.x;       // 0 .. 2*128*1152-1
    int l   = idx / (DD * KCAT);
    int rem = idx % (DD * KCAT);
    int e   = rem / KCAT;
    int md  = rem % KCAT;
    int m = md / DD, d = md % DD;
    const float* W = (l == 0) ? W1 : W2;
    const float* rt = (l == 0) ? r1 : r2;
    float v = (m < 8) ? W[(size_t)m * DD * DD + (size_t)d * DD + e]
                      : rt[(size_t)d * DD + e];
    ((l == 0) ? wc1 : wc2)[rem] = f2bf(v);
}

// per-(dst, r) degree
__global__ __launch_bounds__(256) void hist8_k(const int* __restrict__ dst,
                                               const int* __restrict__ et,
                                               unsigned int* __restrict__ deg8) {
    int e = blockIdx.x * 256 + threadIdx.x;
    if (e >= NE) return;
    atomicAdd(&deg8[(size_t)dst[e] * 8 + et[e]], 1u);
}

// Per node: ×4-padded segment base (unordered alloc); tail filled with
// zero-row dummies (src=ZROW, r=0, deg=1 -> contributes rcp(1)*0 = 0).
__global__ __launch_bounds__(256) void offs_k(const unsigned int* __restrict__ deg8,
                                              unsigned int* __restrict__ counter,
                                              unsigned int* __restrict__ posN,
                                              unsigned int* __restrict__ segBeg,
                                              unsigned int* __restrict__ segLen,
                                              unsigned int* __restrict__ sorted) {
    int node = blockIdx.x * 256 + threadIdx.x;
    if (node >= NN) return;
    const uint4* dp = reinterpret_cast<const uint4*>(&deg8[(size_t)node * 8]);
    uint4 a = dp[0], b = dp[1];
    unsigned int tot = a.x + a.y + a.z + a.w + b.x + b.y + b.z + b.w;
    unsigned int padTot = (tot + 3u) & ~3u;
    unsigned int base = atomicAdd(counter, padTot);
    posN[node]   = base;
    segBeg[node] = base;
    segLen[node] = padTot;
    const unsigned int dummy = (unsigned int)ZROW | (0u << 17) | (1u << 20);
    for (unsigned int p = base + tot; p < base + padTot; ++p)
        sorted[p] = dummy;
}

// scatter src | r<<17 | deg<<20 into per-node slots (bumps posN)
__global__ __launch_bounds__(256) void fill_k(const int* __restrict__ src,
                                              const int* __restrict__ dst,
                                              const int* __restrict__ et,
                                              const unsigned int* __restrict__ deg8,
                                              unsigned int* __restrict__ posN,
                                              unsigned int* __restrict__ sorted) {
    int e = blockIdx.x * 256 + threadIdx.x;
    if (e >= NE) return;
    int d = dst[e], r = et[e];
    unsigned int p = atomicAdd(&posN[d], 1u);
    unsigned int dg = deg8[(size_t)d * 8 + r];
    if (dg > 2047u) dg = 2047u;
    sorted[p] = (unsigned int)src[e] | ((unsigned int)r << 17) | (dg << 20);
}

// Fused RGCN layer, v3. Block = 512 thr = 8 waves = 16 dst nodes (2/wave).
// Phase 1: 4 edges per step; lane group g (16 lanes) gathers the full row of
//          edge j+g via dwordx4; pre-scale by rcp(deg); ds_add_f32 into the
//          padded f32 LDS slice of that edge's relation. No run tracking.
// Phase 2: wave w computes out[16 nodes][cols 16w..16w+15] via MFMA from the
//          f32 LDS (cvt_pk to bf16 fragments) x Wcat.
// mode 1: bf16 store (next layer input); mode 2: f32 store (final output).
__global__ __launch_bounds__(512) void fused_k(const unsigned short* __restrict__ xb,
                                               const unsigned short* __restrict__ wcat,
                                               const float* __restrict__ bias,
                                               const unsigned int* __restrict__ sorted,
                                               const unsigned int* __restrict__ segBeg,
                                               const unsigned int* __restrict__ segLen,
                                               unsigned short* __restrict__ obf,
                                               float* __restrict__ of32,
                                               int mode) {
    __shared__ float ldsf[16 * ROW_STRIDE];         // 110,848 B
    const int wave = threadIdx.x >> 6;              // 0..7
    const int lane = threadIdx.x & 63;
    const int c16  = lane & 15;
    const int grp  = lane >> 4;                     // edge group / frag group
    const int blk  = blockIdx.x;

    // ---------- zero LDS ----------
    for (int i = threadIdx.x; i < 16 * ROW_STRIDE; i += 512)
        ldsf[i] = 0.f;
    __syncthreads();

    // ---------- phase 1: gather + atomic aggregate (2 nodes per wave) ----------
    for (int nl = 0; nl < 2; ++nl) {
        const int row  = wave * 2 + nl;             // LDS row 0..15
        const int node = blk * 16 + row;            // < NN (6250*16 == NN)
        const float* ldsrow = ldsf + row * ROW_STRIDE;

        // root slice (m=8): x[node] bf16 -> f32, elems 2*lane, 2*lane+1
        {
            unsigned int w32 = *reinterpret_cast<const unsigned int*>(
                xb + (size_t)node * DD + lane * 2);
            union { unsigned int u; float f; } lo, hi;
            lo.u = w32 << 16; hi.u = w32 & 0xffff0000u;
            int e = lane * 2;
            float* p = const_cast<float*>(ldsrow) + 8 * SL_STRIDE
                     + (e >> 3) * CH_STRIDE + (e & 7);
            p[0] = lo.f; p[1] = hi.f;
        }

        const unsigned int beg =
            (unsigned int)__builtin_amdgcn_readfirstlane((int)segBeg[node]);
        const unsigned int lenP =
            (unsigned int)__builtin_amdgcn_readfirstlane((int)segLen[node]);
        const unsigned int* segp = sorted + beg;

        for (unsigned int j = 0; j < lenP; j += 4) {
            // per-lane record: group g's record (16 lanes broadcast-load same dword)
            unsigned int rec = segp[j + grp];
            unsigned int srcN = rec & 0x1FFFFu;
            unsigned int r    = (rec >> 17) & 7u;
            float sc = __builtin_amdgcn_rcpf((float)(rec >> 20));
            // full row of this group's edge: 16 lanes x 16B = 256B
            uint4 q = *reinterpret_cast<const uint4*>(
                xb + (size_t)srcN * DD + c16 * 8);
            float* basep = const_cast<float*>(ldsrow) + r * SL_STRIDE
                         + c16 * CH_STRIDE;
            union { unsigned int u; float f; } lo, hi;
#pragma unroll
            for (int k = 0; k < 4; ++k) {
                unsigned int w32 = (&q.x)[k];
                lo.u = w32 << 16; hi.u = w32 & 0xffff0000u;
                atomicAdd(basep + 2 * k,     lo.f * sc);
                atomicAdd(basep + 2 * k + 1, hi.f * sc);
            }
        }
    }
    __syncthreads();

    // ---------- phase 2: MFMA out = xagg @ Wcat^T (wave w -> col tile w) ----------
    f32x4 acc = f32x4{0.f, 0.f, 0.f, 0.f};
    const unsigned short* arow = wcat + (size_t)(wave * 16 + c16) * KCAT;
    const float* brow = ldsf + c16 * ROW_STRIDE;
#pragma unroll
    for (int kk = 0; kk < KCAT / 32; ++kk) {        // 36 k-steps
        int g8 = kk * 4 + grp;                      // 8-elem chunk index 0..143
        const float* cp = brow + (g8 >> 4) * SL_STRIDE + (g8 & 15) * CH_STRIDE;
        f32x4 f0 = *reinterpret_cast<const f32x4*>(cp);
        f32x4 f1 = *reinterpret_cast<const f32x4*>(cp + 4);
        unsigned int p0, p1, p2, p3;
        asm volatile("v_cvt_pk_bf16_f32 %0, %1, %2" : "=v"(p0) : "v"(f0[0]), "v"(f0[1]));
        asm volatile("v_cvt_pk_bf16_f32 %0, %1, %2" : "=v"(p1) : "v"(f0[2]), "v"(f0[3]));
        asm volatile("v_cvt_pk_bf16_f32 %0, %1, %2" : "=v"(p2) : "v"(f1[0]), "v"(f1[1]));
        asm volatile("v_cvt_pk_bf16_f32 %0, %1, %2" : "=v"(p3) : "v"(f1[2]), "v"(f1[3]));
        union { unsigned int u[4]; bf16x8 v; } bfr;
        bfr.u[0] = p0; bfr.u[1] = p1; bfr.u[2] = p2; bfr.u[3] = p3;
        bf16x8 a = *reinterpret_cast<const bf16x8*>(arow + kk * 32 + grp * 8);
        acc = __builtin_amdgcn_mfma_f32_16x16x32_bf16(a, bfr.v, acc, 0, 0, 0);
    }

    // ---------- epilogue: +bias, relu, store ----------
    const int node = blk * 16 + c16;
    const int od = wave * 16 + grp * 4;
    const float4 bv = *reinterpret_cast<const float4*>(bias + od);
    float o0 = fmaxf(acc[0] + bv.x, 0.f);
    float o1 = fmaxf(acc[1] + bv.y, 0.f);
    float o2 = fmaxf(acc[2] + bv.z, 0.f);
    float o3 = fmaxf(acc[3] + bv.w, 0.f);
    if (mode == 1) {
        union { unsigned short s[4]; uint2 v; } pko;
        pko.s[0] = f2bf(o0); pko.s[1] = f2bf(o1);
        pko.s[2] = f2bf(o2); pko.s[3] = f2bf(o3);
        *reinterpret_cast<uint2*>(obf + (size_t)node * DD + od) = pko.v;
    } else {
        *reinterpret_cast<float4*>(of32 + (size_t)node * DD + od)
            = make_float4(o0, o1, o2, o3);
    }
}

extern "C" void kernel_launch(void* const* d_in, const int* in_sizes, int n_in,
                              void* d_out, int out_size, void* d_ws, size_t ws_size,
                              hipStream_t stream) {
    const float* x  = (const float*)d_in[0];
    const int*   ei = (const int*)d_in[1];
    const int*   et = (const int*)d_in[2];
    const float* W1 = (const float*)d_in[3];
    const float* r1 = (const float*)d_in[4];
    const float* b1 = (const float*)d_in[5];
    const float* W2 = (const float*)d_in[6];
    const float* r2 = (const float*)d_in[7];
    const float* b2 = (const float*)d_in[8];
    float* out = (float*)d_out;

    // workspace (~62 MB)
    char* ws = (char*)d_ws;
    unsigned int*   deg8    = (unsigned int*)ws;                 // NN*8 u32 = 3.2 MB
    unsigned int*   counter = deg8 + (size_t)NN * 8;             // 1 u32 (pad 64)
    unsigned int*   posN    = counter + 64;                      // NN u32
    unsigned int*   segBeg  = posN + NN;                         // NN u32
    unsigned int*   segLen  = segBeg + NN;                       // NN u32
    unsigned int*   sorted  = segLen + NN;                       // (NE+3*NN) u32 = 5.2 MB
    unsigned short* wc1     = (unsigned short*)(sorted + NE + 3 * NN); // 294,912 B
    unsigned short* wc2     = wc1 + DD * KCAT;
    unsigned short* xbuf    = wc2 + DD * KCAT;                   // (NN+1)*DD bf16
    unsigned short* xbuf2   = xbuf + (size_t)(NN + 1) * DD;      // (NN+1)*DD bf16
    size_t need = (size_t)((char*)(xbuf2 + (size_t)(NN + 1) * DD) - ws);
    if (ws_size < need) return;                                  // loud failure

    const int* srcv = ei;
    const int* dstv = ei + NE;

    hipMemsetAsync(deg8, 0, ((size_t)NN * 8 + 64) * 4, stream);  // deg8 + counter
    hipMemsetAsync(xbuf  + (size_t)NN * DD, 0, DD * 2, stream);  // ZROW layer-1 input
    hipMemsetAsync(xbuf2 + (size_t)NN * DD, 0, DD * 2, stream);  // ZROW layer-2 input
    cvt_x_k<<<(NN * DD / 4) / 256, 256, 0, stream>>>(x, xbuf, NN * DD / 4);
    cvt_w_k<<<(2 * DD * KCAT) / 256, 256, 0, stream>>>(W1, r1, W2, r2, wc1, wc2);
    hist8_k<<<(NE + 255) / 256, 256, 0, stream>>>(dstv, et, deg8);
    offs_k<<<(NN + 255) / 256, 256, 0, stream>>>(deg8, counter, posN, segBeg, segLen, sorted);
    fill_k<<<(NE + 255) / 256, 256, 0, stream>>>(srcv, dstv, et, deg8, posN, sorted);

    fused_k<<<NBLK, 512, 0, stream>>>(xbuf,  wc1, b1, sorted, segBeg, segLen,
                                      xbuf2, (float*)nullptr, 1);
    fused_k<<<NBLK, 512, 0, stream>>>(xbuf2, wc2, b2, sorted, segBeg, segLen,
                                      (unsigned short*)nullptr, out, 2);
}

// Round 9
// 2142.612 us; speedup vs baseline: 1.0273x; 1.0273x over previous
//
#include <hip/hip_runtime.h>
#include <hip/hip_bf16.h>

#define NN 100000
#define NE 1000000
#define DD 128
#define KCAT 1152              // 9*128 (8 relations + root)

typedef short bf16x8 __attribute__((ext_vector_type(8)));
typedef float f32x4 __attribute__((ext_vector_type(4)));

__device__ __forceinline__ unsigned short f2bf(float f) {
    union { float f; unsigned int u; } c; c.f = f;
    unsigned int u = c.u;
    u += 0x7fffu + ((u >> 16) & 1u);    // round-to-nearest-even
    return (unsigned short)(u >> 16);
}

// fp32 -> bf16, 4 elems/thread
__global__ __launch_bounds__(256) void cvt_x_k(const float* __restrict__ in,
                                               unsigned short* __restrict__ out,
                                               int n4) {
    int i = blockIdx.x * 256 + threadIdx.x;
    if (i >= n4) return;
    float4 v = reinterpret_cast<const float4*>(in)[i];
    ushort4 o;
    o.x = f2bf(v.x); o.y = f2bf(v.y); o.z = f2bf(v.z); o.w = f2bf(v.w);
    reinterpret_cast<ushort4*>(out)[i] = o;
}

// Build Wcat[e][m*128+d] = W[m][d][e] (m<8) / root[d][e] (m==8), bf16, both layers.
__global__ __launch_bounds__(256) void cvt_w_k(const float* __restrict__ W1,
                                               const float* __restrict__ r1,
                                               const float* __restrict__ W2,
                                               const float* __restrict__ r2,
                                               unsigned short* __restrict__ wc1,
                                               unsigned short* __restrict__ wc2) {
    int idx = blockIdx.x * 256 + threadIdx.x;       // 0 .. 2*128*1152-1
    int l   = idx / (DD * KCAT);
    int rem = idx % (DD * KCAT);
    int e   = rem / KCAT;
    int md  = rem % KCAT;
    int m = md / DD, d = md % DD;
    const float* W = (l == 0) ? W1 : W2;
    const float* rt = (l == 0) ? r1 : r2;
    float v = (m < 8) ? W[(size_t)m * DD * DD + (size_t)d * DD + e]
                      : rt[(size_t)d * DD + e];
    ((l == 0) ? wc1 : wc2)[rem] = f2bf(v);
}

// per-(dst,r) degree + per-src out-degree (posS doubles as count)
__global__ __launch_bounds__(256) void hist_k(const int* __restrict__ src,
                                              const int* __restrict__ dst,
                                              const int* __restrict__ et,
                                              unsigned int* __restrict__ deg8,
                                              unsigned int* __restrict__ posS) {
    int e = blockIdx.x * 256 + threadIdx.x;
    if (e >= NE) return;
    atomicAdd(&deg8[(size_t)dst[e] * 8 + et[e]], 1u);
    atomicAdd(&posS[src[e]], 1u);
}

// Per node: dst-side (d,r)-grouped slot alloc (chunked by node half) and
// src-side offsets (in-place count -> base).
__global__ __launch_bounds__(256) void offs_k(const unsigned int* __restrict__ deg8,
                                              unsigned int* __restrict__ cnts,
                                              unsigned int* __restrict__ pos8,
                                              unsigned int* __restrict__ posS,
                                              unsigned int* __restrict__ segBeg,
                                              unsigned int* __restrict__ segLen,
                                              unsigned int CAP, int nch) {
    int node = blockIdx.x * 256 + threadIdx.x;
    if (node >= NN) return;
    const uint4* dp = reinterpret_cast<const uint4*>(&deg8[(size_t)node * 8]);
    uint4 a = dp[0], b = dp[1];
    unsigned int tot = a.x + a.y + a.z + a.w + b.x + b.y + b.z + b.w;
    int c = (nch == 2 && node >= NN / 2) ? 1 : 0;
    unsigned int base = atomicAdd(&cnts[c], tot) + (unsigned int)c * CAP;
    unsigned int* pp = &pos8[(size_t)node * 8];
    unsigned int run = base;
    pp[0] = run; run += a.x;  pp[1] = run; run += a.y;
    pp[2] = run; run += a.z;  pp[3] = run; run += a.w;
    pp[4] = run; run += b.x;  pp[5] = run; run += b.y;
    pp[6] = run; run += b.z;  pp[7] = run; run += b.w;
    segBeg[node] = base;
    segLen[node] = tot;
    // src side: count -> base
    unsigned int q0 = atomicAdd(&cnts[2], posS[node]);
    posS[node] = q0;
}

// Per edge: assign dst-slot p ((d,r)-grouped) and src-sorted position q.
// recD[p] = r; recA[q] = src | deg<<17; recB[q] = p.
__global__ __launch_bounds__(256) void fill_k(const int* __restrict__ src,
                                              const int* __restrict__ dst,
                                              const int* __restrict__ et,
                                              const unsigned int* __restrict__ deg8,
                                              unsigned int* __restrict__ pos8,
                                              unsigned int* __restrict__ posS,
                                              unsigned int* __restrict__ recA,
                                              unsigned int* __restrict__ recB,
                                              unsigned char* __restrict__ recD) {
    int e = blockIdx.x * 256 + threadIdx.x;
    if (e >= NE) return;
    int s = src[e], d = dst[e], r = et[e];
    unsigned int p = atomicAdd(&pos8[(size_t)d * 8 + r], 1u);
    recD[p] = (unsigned char)r;
    unsigned int q = atomicAdd(&posS[s], 1u);
    unsigned int dg = deg8[(size_t)d * 8 + r];
    if (dg > 2047u) dg = 2047u;
    recA[q] = (unsigned int)s | (dg << 17);
    recB[q] = p;
}

// Spread: walk edges in src-sorted order (x-row L1 reuse), pre-scale by
// rcp(deg), write 256B row to its dst-sorted slot (non-temporal).
// 625 blocks x 512 thr = 5000 waves x 200 edges (exact).
__global__ __launch_bounds__(512) void spread_k(const unsigned short* __restrict__ xb,
                                                const unsigned int* __restrict__ recA,
                                                const unsigned int* __restrict__ recB,
                                                unsigned short* __restrict__ y,
                                                unsigned int chunkOff, unsigned int CAP) {
    const int gw   = blockIdx.x * 8 + (threadIdx.x >> 6);   // 0..4999
    const int lane = threadIdx.x & 63;
    const int b0   = gw * 200;

    for (int b = 0; b < 200; b += 8) {
        int j = b0 + b;                                     // multiple of 8
        uint4 a0 = *reinterpret_cast<const uint4*>(recA + j);
        uint4 a1 = *reinterpret_cast<const uint4*>(recA + j + 4);
        uint4 s0 = *reinterpret_cast<const uint4*>(recB + j);
        uint4 s1 = *reinterpret_cast<const uint4*>(recB + j + 4);
        unsigned int pk[8] = {a0.x, a0.y, a0.z, a0.w, a1.x, a1.y, a1.z, a1.w};
        unsigned int sl[8] = {s0.x, s0.y, s0.z, s0.w, s1.x, s1.y, s1.z, s1.w};
        unsigned int hv[8];
#pragma unroll
        for (int u = 0; u < 8; ++u) {
            unsigned int rel = sl[u] - chunkOff;
            if (rel < CAP)
                hv[u] = *reinterpret_cast<const unsigned int*>(
                    xb + (size_t)(pk[u] & 0x1FFFFu) * DD + lane * 2);
        }
#pragma unroll
        for (int u = 0; u < 8; ++u) {
            unsigned int rel = sl[u] - chunkOff;
            if (rel < CAP) {
                float sc = __builtin_amdgcn_rcpf((float)(pk[u] >> 17));
                union { unsigned int u32; float f; } lo, hi;
                lo.u32 = hv[u] << 16; hi.u32 = hv[u] & 0xffff0000u;
                float flo = lo.f * sc, fhi = hi.f * sc;
                unsigned int w32;
                asm volatile("v_cvt_pk_bf16_f32 %0, %1, %2"
                             : "=v"(w32) : "v"(flo), "v"(fhi));
                __builtin_nontemporal_store(w32,
                    reinterpret_cast<unsigned int*>(y + (size_t)rel * DD + lane * 2));
            }
        }
    }
}

// Aggregate layer: block = 512 thr = 8 waves = 16 dst nodes (2/wave).
// Phase 1: sequential y-segment read, run-flush per relation (sum; scale was
//          pre-applied) into swizzled bf16 LDS; root x at slice 8.
// Phase 2: out[16][128] = xagg @ Wcat^T via MFMA, +bias, relu.
// mode 1: bf16 store (next layer input); mode 2: f32 store (final output).
__global__ __launch_bounds__(512) void agg_k(const unsigned short* __restrict__ xb,
                                             const unsigned short* __restrict__ wcat,
                                             const float* __restrict__ bias,
                                             const unsigned char* __restrict__ recD,
                                             const unsigned int* __restrict__ segBeg,
                                             const unsigned int* __restrict__ segLen,
                                             const unsigned short* __restrict__ y,
                                             unsigned int chunkOff, int nodeLo,
                                             unsigned short* __restrict__ obf,
                                             float* __restrict__ of32,
                                             int mode) {
    __shared__ unsigned short ldsx[16 * KCAT];      // 36,864 B
    const int wave = threadIdx.x >> 6;              // 0..7
    const int lane = threadIdx.x & 63;
    const int c16  = lane & 15;
    const int grp  = lane >> 4;
    const int lq   = lane >> 2;
    const int lm   = lane & 3;
    const int blk  = blockIdx.x;
    unsigned int* lds32 = reinterpret_cast<unsigned int*>(ldsx);

    // ---------- phase 1: sequential segment read + run-flush ----------
    for (int nl = 0; nl < 2; ++nl) {
        const int row  = wave * 2 + nl;             // LDS row 0..15
        const int node = nodeLo + blk * 16 + row;
        const int sbase = row * (KCAT / 2);         // u32 units per row
        const int xorv = row & 7;

        // zero relation slices; write root slice (m=8)
#pragma unroll
        for (int r = 0; r < 8; ++r)
            lds32[sbase + (((r * 16 + lq) ^ xorv) << 2) + lm] = 0u;
        lds32[sbase + (((128 + lq) ^ xorv) << 2) + lm] =
            *reinterpret_cast<const unsigned int*>(xb + (size_t)node * DD + lane * 2);

        const unsigned int beg = segBeg[node];
        const unsigned int len = segLen[node];
        const unsigned char* rp = recD + beg;
        const unsigned short* yb = y + (size_t)(beg - chunkOff) * DD;

        float ax = 0.f, ay = 0.f;
        unsigned int rc = 15u;
        for (unsigned int j = 0; j < len; j += 8) {
            int n = (int)(len - j); if (n > 8) n = 8;
            unsigned int hv[8]; unsigned char rr[8];
#pragma unroll
            for (int u = 0; u < 8; ++u)
                if (u < n) {
                    rr[u] = rp[j + u];
                    hv[u] = *reinterpret_cast<const unsigned int*>(
                        yb + (size_t)(j + u) * DD + lane * 2);
                }
#pragma unroll
            for (int u = 0; u < 8; ++u)
                if (u < n) {
                    unsigned int r = rr[u];
                    if (r != rc) {
                        if (rc < 8u) {
                            unsigned int w32 = ((unsigned int)f2bf(ay) << 16)
                                             | (unsigned int)f2bf(ax);
                            lds32[sbase + ((((int)rc * 16 + lq) ^ xorv) << 2) + lm] = w32;
                        }
                        rc = r; ax = 0.f; ay = 0.f;
                    }
                    union { unsigned int u32; float f; } lo, hi;
                    lo.u32 = hv[u] << 16; hi.u32 = hv[u] & 0xffff0000u;
                    ax += lo.f; ay += hi.f;
                }
        }
        if (rc < 8u) {
            unsigned int w32 = ((unsigned int)f2bf(ay) << 16)
                             | (unsigned int)f2bf(ax);
            lds32[sbase + ((((int)rc * 16 + lq) ^ xorv) << 2) + lm] = w32;
        }
    }
    __syncthreads();

    // ---------- phase 2: MFMA out = xagg @ Wcat^T (wave w -> col tile w) ----------
    f32x4 acc = f32x4{0.f, 0.f, 0.f, 0.f};
    const unsigned short* arow = wcat + (size_t)(wave * 16 + c16) * KCAT;
#pragma unroll
    for (int kk = 0; kk < KCAT / 32; ++kk) {        // 36 k-steps
        int slot = (kk * 4 + grp) ^ (c16 & 7);
        bf16x8 b = *reinterpret_cast<const bf16x8*>(&ldsx[c16 * KCAT + slot * 8]);
        bf16x8 a = *reinterpret_cast<const bf16x8*>(arow + kk * 32 + grp * 8);
        acc = __builtin_amdgcn_mfma_f32_16x16x32_bf16(a, b, acc, 0, 0, 0);
    }

    // ---------- epilogue: +bias, relu, store ----------
    const int node = nodeLo + blk * 16 + c16;
    const int od = wave * 16 + grp * 4;
    const float4 bv = *reinterpret_cast<const float4*>(bias + od);
    float o0 = fmaxf(acc[0] + bv.x, 0.f);
    float o1 = fmaxf(acc[1] + bv.y, 0.f);
    float o2 = fmaxf(acc[2] + bv.z, 0.f);
    float o3 = fmaxf(acc[3] + bv.w, 0.f);
    if (mode == 1) {
        union { unsigned short s[4]; uint2 v; } pko;
        pko.s[0] = f2bf(o0); pko.s[1] = f2bf(o1);
        pko.s[2] = f2bf(o2); pko.s[3] = f2bf(o3);
        *reinterpret_cast<uint2*>(obf + (size_t)node * DD + od) = pko.v;
    } else {
        *reinterpret_cast<float4*>(of32 + (size_t)node * DD + od)
            = make_float4(o0, o1, o2, o3);
    }
}

extern "C" void kernel_launch(void* const* d_in, const int* in_sizes, int n_in,
                              void* d_out, int out_size, void* d_ws, size_t ws_size,
                              hipStream_t stream) {
    const float* x  = (const float*)d_in[0];
    const int*   ei = (const int*)d_in[1];
    const int*   et = (const int*)d_in[2];
    const float* W1 = (const float*)d_in[3];
    const float* r1 = (const float*)d_in[4];
    const float* b1 = (const float*)d_in[5];
    const float* W2 = (const float*)d_in[6];
    const float* r2 = (const float*)d_in[7];
    const float* b2 = (const float*)d_in[8];
    float* out = (float*)d_out;

    // ---- fixed workspace layout (~67.5 MB) ----
    char* ws = (char*)d_ws;
    unsigned int*   deg8   = (unsigned int*)ws;                   // NN*8 u32
    unsigned int*   cnts   = deg8 + (size_t)NN * 8;               // 64 u32
    unsigned int*   posS   = cnts + 64;                           // NN u32
    unsigned int*   pos8   = posS + NN;                           // NN*8 u32
    unsigned int*   segBeg = pos8 + (size_t)NN * 8;               // NN u32
    unsigned int*   segLen = segBeg + NN;                         // NN u32
    unsigned int*   recA   = segLen + NN;                         // NE u32
    unsigned int*   recB   = recA + NE;                           // NE u32
    unsigned short* wc1    = (unsigned short*)(recB + NE);        // 294,912 B
    unsigned short* wc2    = wc1 + DD * KCAT;
    unsigned short* xbuf   = wc2 + DD * KCAT;                     // 25.6 MB
    unsigned short* xbuf2  = xbuf + (size_t)NN * DD;              // 25.6 MB
    size_t fixedEnd = (size_t)((char*)(xbuf2 + (size_t)NN * DD) - ws);
    fixedEnd = (fixedEnd + 255) & ~(size_t)255;

    // ---- adaptive y / recD sizing ----
    if (ws_size < fixedEnd + 1024) return;
    size_t avail = ws_size - fixedEnd - 512;
    int nch; unsigned int CAP;
    if (avail >= (size_t)NE * 257) { nch = 1; CAP = NE; }
    else {
        nch = 2;
        CAP = (unsigned int)(avail / 258);
        if (CAP < 530000u) return;                  // loud failure
        if (CAP > NE) CAP = NE;
    }
    unsigned char* recD = (unsigned char*)(ws + fixedEnd);        // nch*CAP B
    size_t yOff = (fixedEnd + (size_t)nch * CAP + 255) & ~(size_t)255;
    unsigned short* y = (unsigned short*)(ws + yOff);             // CAP*256 B

    const int* srcv = ei;
    const int* dstv = ei + NE;

    hipMemsetAsync(deg8, 0, (size_t)NN * 8 * 4 + 256 + (size_t)NN * 4, stream);
    cvt_x_k<<<(NN * DD / 4) / 256, 256, 0, stream>>>(x, xbuf, NN * DD / 4);
    cvt_w_k<<<(2 * DD * KCAT) / 256, 256, 0, stream>>>(W1, r1, W2, r2, wc1, wc2);
    hist_k<<<(NE + 255) / 256, 256, 0, stream>>>(srcv, dstv, et, deg8, posS);
    offs_k<<<(NN + 255) / 256, 256, 0, stream>>>(deg8, cnts, pos8, posS,
                                                 segBeg, segLen, CAP, nch);
    fill_k<<<(NE + 255) / 256, 256, 0, stream>>>(srcv, dstv, et, deg8, pos8, posS,
                                                 recA, recB, recD);

    const int nodesPer = NN / nch;                  // 100000 or 50000
    const int aggBlocks = nodesPer / 16;            // 6250 or 3125
    for (int layer = 0; layer < 2; ++layer) {
        const unsigned short* in = layer ? xbuf2 : xbuf;
        const unsigned short* wc = layer ? wc2 : wc1;
        const float* bb = layer ? b2 : b1;
        for (int c = 0; c < nch; ++c) {
            unsigned int chunkOff = (unsigned int)c * CAP;
            spread_k<<<625, 512, 0, stream>>>(in, recA, recB, y, chunkOff, CAP);
            agg_k<<<aggBlocks, 512, 0, stream>>>(in, wc, bb, recD, segBeg, segLen,
                                                 y, chunkOff, c * nodesPer,
                                                 layer ? (unsigned short*)nullptr : xbuf2,
                                                 layer ? out : (float*)nullptr,
                                                 layer ? 2 : 1);
        }
    }
}

// Round 10
// 2140.236 us; speedup vs baseline: 1.0285x; 1.0011x over previous
//
#include <hip/hip_runtime.h>
#include <hip/hip_bf16.h>

#define NN 100000
#define NE 1000000
#define DD 128
#define KCAT 1152              // 9*128 (8 relations + root)

typedef short bf16x8 __attribute__((ext_vector_type(8)));
typedef float f32x4 __attribute__((ext_vector_type(4)));

__device__ __forceinline__ unsigned short f2bf(float f) {
    union { float f; unsigned int u; } c; c.f = f;
    unsigned int u = c.u;
    u += 0x7fffu + ((u >> 16) & 1u);    // round-to-nearest-even
    return (unsigned short)(u >> 16);
}

// fp32 -> bf16, 4 elems/thread
__global__ __launch_bounds__(256) void cvt_x_k(const float* __restrict__ in,
                                               unsigned short* __restrict__ out,
                                               int n4) {
    int i = blockIdx.x * 256 + threadIdx.x;
    if (i >= n4) return;
    float4 v = reinterpret_cast<const float4*>(in)[i];
    ushort4 o;
    o.x = f2bf(v.x); o.y = f2bf(v.y); o.z = f2bf(v.z); o.w = f2bf(v.w);
    reinterpret_cast<ushort4*>(out)[i] = o;
}

// Build Wcat[e][m*128+d] = W[m][d][e] (m<8) / root[d][e] (m==8), bf16, both layers.
__global__ __launch_bounds__(256) void cvt_w_k(const float* __restrict__ W1,
                                               const float* __restrict__ r1,
                                               const float* __restrict__ W2,
                                               const float* __restrict__ r2,
                                               unsigned short* __restrict__ wc1,
                                               unsigned short* __restrict__ wc2) {
    int idx = blockIdx.x * 256 + threadIdx.x;       // 0 .. 2*128*1152-1
    int l   = idx / (DD * KCAT);
    int rem = idx % (DD * KCAT);
    int e   = rem / KCAT;
    int md  = rem % KCAT;
    int m = md / DD, d = md % DD;
    const float* W = (l == 0) ? W1 : W2;
    const float* rt = (l == 0) ? r1 : r2;
    float v = (m < 8) ? W[(size_t)m * DD * DD + (size_t)d * DD + e]
                      : rt[(size_t)d * DD + e];
    ((l == 0) ? wc1 : wc2)[rem] = f2bf(v);
}

// per-(dst,r) degree + per-src out-degree (posS doubles as count)
__global__ __launch_bounds__(256) void hist_k(const int* __restrict__ src,
                                              const int* __restrict__ dst,
                                              const int* __restrict__ et,
                                              unsigned int* __restrict__ deg8,
                                              unsigned int* __restrict__ posS) {
    int e = blockIdx.x * 256 + threadIdx.x;
    if (e >= NE) return;
    atomicAdd(&deg8[(size_t)dst[e] * 8 + et[e]], 1u);
    atomicAdd(&posS[src[e]], 1u);
}

// Per node: dst-side (d,r)-grouped slot alloc (chunked by node half) and
// src-side offsets (in-place count -> base).
__global__ __launch_bounds__(256) void offs_k(const unsigned int* __restrict__ deg8,
                                              unsigned int* __restrict__ cnts,
                                              unsigned int* __restrict__ pos8,
                                              unsigned int* __restrict__ posS,
                                              unsigned int* __restrict__ segBeg,
                                              unsigned int* __restrict__ segLen,
                                              unsigned int CAP, int nch) {
    int node = blockIdx.x * 256 + threadIdx.x;
    if (node >= NN) return;
    const uint4* dp = reinterpret_cast<const uint4*>(&deg8[(size_t)node * 8]);
    uint4 a = dp[0], b = dp[1];
    unsigned int tot = a.x + a.y + a.z + a.w + b.x + b.y + b.z + b.w;
    int c = (nch == 2 && node >= NN / 2) ? 1 : 0;
    unsigned int base = atomicAdd(&cnts[c], tot) + (unsigned int)c * CAP;
    unsigned int* pp = &pos8[(size_t)node * 8];
    unsigned int run = base;
    pp[0] = run; run += a.x;  pp[1] = run; run += a.y;
    pp[2] = run; run += a.z;  pp[3] = run; run += a.w;
    pp[4] = run; run += b.x;  pp[5] = run; run += b.y;
    pp[6] = run; run += b.z;  pp[7] = run; run += b.w;
    segBeg[node] = base;
    segLen[node] = tot;
    // src side: count -> base
    unsigned int q0 = atomicAdd(&cnts[2], posS[node]);
    posS[node] = q0;
}

// Per edge: assign dst-slot p ((d,r)-grouped) and src-sorted position q.
// recD[p] = r; recA[q] = src | deg<<17; recB[q] = p.
__global__ __launch_bounds__(256) void fill_k(const int* __restrict__ src,
                                              const int* __restrict__ dst,
                                              const int* __restrict__ et,
                                              const unsigned int* __restrict__ deg8,
                                              unsigned int* __restrict__ pos8,
                                              unsigned int* __restrict__ posS,
                                              unsigned int* __restrict__ recA,
                                              unsigned int* __restrict__ recB,
                                              unsigned char* __restrict__ recD) {
    int e = blockIdx.x * 256 + threadIdx.x;
    if (e >= NE) return;
    int s = src[e], d = dst[e], r = et[e];
    unsigned int p = atomicAdd(&pos8[(size_t)d * 8 + r], 1u);
    recD[p] = (unsigned char)r;
    unsigned int q = atomicAdd(&posS[s], 1u);
    unsigned int dg = deg8[(size_t)d * 8 + r];
    if (dg > 2047u) dg = 2047u;
    recA[q] = (unsigned int)s | (dg << 17);
    recB[q] = p;
}

// Spread: walk edges in src-sorted order (x-row L1 reuse), pre-scale by
// rcp(deg), write 256B row to its dst-sorted slot (non-temporal).
// 625 blocks x 512 thr = 5000 waves x 200 edges (exact).
__global__ __launch_bounds__(512) void spread_k(const unsigned short* __restrict__ xb,
                                                const unsigned int* __restrict__ recA,
                                                const unsigned int* __restrict__ recB,
                                                unsigned short* __restrict__ y,
                                                unsigned int chunkOff, unsigned int CAP) {
    const int gw   = blockIdx.x * 8 + (threadIdx.x >> 6);   // 0..4999
    const int lane = threadIdx.x & 63;
    const int b0   = gw * 200;

    for (int b = 0; b < 200; b += 8) {
        int j = b0 + b;                                     // multiple of 8
        uint4 a0 = *reinterpret_cast<const uint4*>(recA + j);
        uint4 a1 = *reinterpret_cast<const uint4*>(recA + j + 4);
        uint4 s0 = *reinterpret_cast<const uint4*>(recB + j);
        uint4 s1 = *reinterpret_cast<const uint4*>(recB + j + 4);
        unsigned int pk[8] = {a0.x, a0.y, a0.z, a0.w, a1.x, a1.y, a1.z, a1.w};
        unsigned int sl[8] = {s0.x, s0.y, s0.z, s0.w, s1.x, s1.y, s1.z, s1.w};
        unsigned int hv[8];
#pragma unroll
        for (int u = 0; u < 8; ++u) {
            unsigned int rel = sl[u] - chunkOff;
            if (rel < CAP)
                hv[u] = *reinterpret_cast<const unsigned int*>(
                    xb + (size_t)(pk[u] & 0x1FFFFu) * DD + lane * 2);
        }
#pragma unroll
        for (int u = 0; u < 8; ++u) {
            unsigned int rel = sl[u] - chunkOff;
            if (rel < CAP) {
                float sc = __builtin_amdgcn_rcpf((float)(pk[u] >> 17));
                union { unsigned int u32; float f; } lo, hi;
                lo.u32 = hv[u] << 16; hi.u32 = hv[u] & 0xffff0000u;
                float flo = lo.f * sc, fhi = hi.f * sc;
                unsigned int w32;
                asm volatile("v_cvt_pk_bf16_f32 %0, %1, %2"
                             : "=v"(w32) : "v"(flo), "v"(fhi));
                __builtin_nontemporal_store(w32,
                    reinterpret_cast<unsigned int*>(y + (size_t)rel * DD + lane * 2));
            }
        }
    }
}

// Aggregate layer: block = 512 thr = 8 waves = 16 dst nodes (2/wave).
// Phase 1: sequential y-segment read, run-flush per relation (sum; scale was
//          pre-applied) into swizzled bf16 LDS; root x at slice 8.
// Phase 2: out[16][128] = xagg @ Wcat^T via MFMA, +bias, relu.
// mode 1: bf16 store (next layer input); mode 2: f32 store (final output).
__global__ __launch_bounds__(512) void agg_k(const unsigned short* __restrict__ xb,
                                             const unsigned short* __restrict__ wcat,
                                             const float* __restrict__ bias,
                                             const unsigned char* __restrict__ recD,
                                             const unsigned int* __restrict__ segBeg,
                                             const unsigned int* __restrict__ segLen,
                                             const unsigned short* __restrict__ y,
                                             unsigned int chunkOff, int nodeLo,
                                             unsigned short* __restrict__ obf,
                                             float* __restrict__ of32,
                                             int mode) {
    __shared__ unsigned short ldsx[16 * KCAT];      // 36,864 B
    const int wave = threadIdx.x >> 6;              // 0..7
    const int lane = threadIdx.x & 63;
    const int c16  = lane & 15;
    const int grp  = lane >> 4;
    const int lq   = lane >> 2;
    const int lm   = lane & 3;
    const int blk  = blockIdx.x;
    unsigned int* lds32 = reinterpret_cast<unsigned int*>(ldsx);

    // ---------- phase 1: sequential segment read + run-flush ----------
    for (int nl = 0; nl < 2; ++nl) {
        const int row  = wave * 2 + nl;             // LDS row 0..15
        const int node = nodeLo + blk * 16 + row;
        const int sbase = row * (KCAT / 2);         // u32 units per row
        const int xorv = row & 7;

        // zero relation slices; write root slice (m=8)
#pragma unroll
        for (int r = 0; r < 8; ++r)
            lds32[sbase + (((r * 16 + lq) ^ xorv) << 2) + lm] = 0u;
        lds32[sbase + (((128 + lq) ^ xorv) << 2) + lm] =
            *reinterpret_cast<const unsigned int*>(xb + (size_t)node * DD + lane * 2);

        const unsigned int beg = segBeg[node];
        const unsigned int len = segLen[node];
        const unsigned char* rp = recD + beg;
        const unsigned short* yb = y + (size_t)(beg - chunkOff) * DD;

        float ax = 0.f, ay = 0.f;
        unsigned int rc = 15u;
        for (unsigned int j = 0; j < len; j += 8) {
            int n = (int)(len - j); if (n > 8) n = 8;
            unsigned int hv[8]; unsigned char rr[8];
#pragma unroll
            for (int u = 0; u < 8; ++u)
                if (u < n) {
                    rr[u] = rp[j + u];
                    hv[u] = *reinterpret_cast<const unsigned int*>(
                        yb + (size_t)(j + u) * DD + lane * 2);
                }
#pragma unroll
            for (int u = 0; u < 8; ++u)
                if (u < n) {
                    unsigned int r = rr[u];
                    if (r != rc) {
                        if (rc < 8u) {
                            unsigned int w32 = ((unsigned int)f2bf(ay) << 16)
                                             | (unsigned int)f2bf(ax);
                            lds32[sbase + ((((int)rc * 16 + lq) ^ xorv) << 2) + lm] = w32;
                        }
                        rc = r; ax = 0.f; ay = 0.f;
                    }
                    union { unsigned int u32; float f; } lo, hi;
                    lo.u32 = hv[u] << 16; hi.u32 = hv[u] & 0xffff0000u;
                    ax += lo.f; ay += hi.f;
                }
        }
        if (rc < 8u) {
            unsigned int w32 = ((unsigned int)f2bf(ay) << 16)
                             | (unsigned int)f2bf(ax);
            lds32[sbase + ((((int)rc * 16 + lq) ^ xorv) << 2) + lm] = w32;
        }
    }
    __syncthreads();

    // ---------- phase 2: MFMA out = xagg @ Wcat^T (wave w -> col tile w) ----------
    f32x4 acc = f32x4{0.f, 0.f, 0.f, 0.f};
    const unsigned short* arow = wcat + (size_t)(wave * 16 + c16) * KCAT;
#pragma unroll
    for (int kk = 0; kk < KCAT / 32; ++kk) {        // 36 k-steps
        int slot = (kk * 4 + grp) ^ (c16 & 7);
        bf16x8 b = *reinterpret_cast<const bf16x8*>(&ldsx[c16 * KCAT + slot * 8]);
        bf16x8 a = *reinterpret_cast<const bf16x8*>(arow + kk * 32 + grp * 8);
        acc = __builtin_amdgcn_mfma_f32_16x16x32_bf16(a, b, acc, 0, 0, 0);
    }

    // ---------- epilogue: +bias, relu, store ----------
    const int node = nodeLo + blk * 16 + c16;
    const int od = wave * 16 + grp * 4;
    const float4 bv = *reinterpret_cast<const float4*>(bias + od);
    float o0 = fmaxf(acc[0] + bv.x, 0.f);
    float o1 = fmaxf(acc[1] + bv.y, 0.f);
    float o2 = fmaxf(acc[2] + bv.z, 0.f);
    float o3 = fmaxf(acc[3] + bv.w, 0.f);
    if (mode == 1) {
        union { unsigned short s[4]; uint2 v; } pko;
        pko.s[0] = f2bf(o0); pko.s[1] = f2bf(o1);
        pko.s[2] = f2bf(o2); pko.s[3] = f2bf(o3);
        *reinterpret_cast<uint2*>(obf + (size_t)node * DD + od) = pko.v;
    } else {
        *reinterpret_cast<float4*>(of32 + (size_t)node * DD + od)
            = make_float4(o0, o1, o2, o3);
    }
}

extern "C" void kernel_launch(void* const* d_in, const int* in_sizes, int n_in,
                              void* d_out, int out_size, void* d_ws, size_t ws_size,
                              hipStream_t stream) {
    const float* x  = (const float*)d_in[0];
    const int*   ei = (const int*)d_in[1];
    const int*   et = (const int*)d_in[2];
    const float* W1 = (const float*)d_in[3];
    const float* r1 = (const float*)d_in[4];
    const float* b1 = (const float*)d_in[5];
    const float* W2 = (const float*)d_in[6];
    const float* r2 = (const float*)d_in[7];
    const float* b2 = (const float*)d_in[8];
    float* out = (float*)d_out;

    // ---- fixed workspace layout (~67.5 MB) ----
    char* ws = (char*)d_ws;
    unsigned int*   deg8   = (unsigned int*)ws;                   // NN*8 u32
    unsigned int*   cnts   = deg8 + (size_t)NN * 8;               // 64 u32
    unsigned int*   posS   = cnts + 64;                           // NN u32
    unsigned int*   pos8   = posS + NN;                           // NN*8 u32
    unsigned int*   segBeg = pos8 + (size_t)NN * 8;               // NN u32
    unsigned int*   segLen = segBeg + NN;                         // NN u32
    unsigned int*   recA   = segLen + NN;                         // NE u32
    unsigned int*   recB   = recA + NE;                           // NE u32
    unsigned short* wc1    = (unsigned short*)(recB + NE);        // 294,912 B
    unsigned short* wc2    = wc1 + DD * KCAT;
    unsigned short* xbuf   = wc2 + DD * KCAT;                     // 25.6 MB
    unsigned short* xbuf2  = xbuf + (size_t)NN * DD;              // 25.6 MB
    size_t fixedEnd = (size_t)((char*)(xbuf2 + (size_t)NN * DD) - ws);
    fixedEnd = (fixedEnd + 255) & ~(size_t)255;

    // ---- adaptive y / recD sizing ----
    if (ws_size < fixedEnd + 1024) return;
    size_t avail = ws_size - fixedEnd - 512;
    int nch; unsigned int CAP;
    if (avail >= (size_t)NE * 257) { nch = 1; CAP = NE; }
    else {
        nch = 2;
        CAP = (unsigned int)(avail / 258);
        if (CAP < 530000u) return;                  // loud failure
        if (CAP > NE) CAP = NE;
    }
    unsigned char* recD = (unsigned char*)(ws + fixedEnd);        // nch*CAP B
    size_t yOff = (fixedEnd + (size_t)nch * CAP + 255) & ~(size_t)255;
    unsigned short* y = (unsigned short*)(ws + yOff);             // CAP*256 B

    const int* srcv = ei;
    const int* dstv = ei + NE;

    hipMemsetAsync(deg8, 0, (size_t)NN * 8 * 4 + 256 + (size_t)NN * 4, stream);
    cvt_x_k<<<(NN * DD / 4) / 256, 256, 0, stream>>>(x, xbuf, NN * DD / 4);
    cvt_w_k<<<(2 * DD * KCAT) / 256, 256, 0, stream>>>(W1, r1, W2, r2, wc1, wc2);
    hist_k<<<(NE + 255) / 256, 256, 0, stream>>>(srcv, dstv, et, deg8, posS);
    offs_k<<<(NN + 255) / 256, 256, 0, stream>>>(deg8, cnts, pos8, posS,
                                                 segBeg, segLen, CAP, nch);
    fill_k<<<(NE + 255) / 256, 256, 0, stream>>>(srcv, dstv, et, deg8, pos8, posS,
                                                 recA, recB, recD);

    const int nodesPer = NN / nch;                  // 100000 or 50000
    const int aggBlocks = nodesPer / 16;            // 6250 or 3125
    for (int layer = 0; layer < 2; ++layer) {
        const unsigned short* in = layer ? xbuf2 : xbuf;
        const unsigned short* wc = layer ? wc2 : wc1;
        const float* bb = layer ? b2 : b1;
        for (int c = 0; c < nch; ++c) {
            unsigned int chunkOff = (unsigned int)c * CAP;
            spread_k<<<625, 512, 0, stream>>>(in, recA, recB, y, chunkOff, CAP);
            agg_k<<<aggBlocks, 512, 0, stream>>>(in, wc, bb, recD, segBeg, segLen,
                                                 y, chunkOff, c * nodesPer,
                                                 layer ? (unsigned short*)nullptr : xbuf2,
                                                 layer ? out : (float*)nullptr,
                                                 layer ? 2 : 1);
        }
    }
}

// Round 11
// 2138.596 us; speedup vs baseline: 1.0293x; 1.0008x over previous
//
#include <hip/hip_runtime.h>
#include <hip/hip_bf16.h>

#define NN 100000
#define NE 1000000
#define DD 128
#define KCAT 1152              // 9*128 (8 relations + root)

typedef short bf16x8 __attribute__((ext_vector_type(8)));
typedef float f32x4 __attribute__((ext_vector_type(4)));

__device__ __forceinline__ unsigned short f2bf(float f) {
    union { float f; unsigned int u; } c; c.f = f;
    unsigned int u = c.u;
    u += 0x7fffu + ((u >> 16) & 1u);    // round-to-nearest-even
    return (unsigned short)(u >> 16);
}

// fp32 -> bf16, 4 elems/thread
__global__ __launch_bounds__(256) void cvt_x_k(const float* __restrict__ in,
                                               unsigned short* __restrict__ out,
                                               int n4) {
    int i = blockIdx.x * 256 + threadIdx.x;
    if (i >= n4) return;
    float4 v = reinterpret_cast<const float4*>(in)[i];
    ushort4 o;
    o.x = f2bf(v.x); o.y = f2bf(v.y); o.z = f2bf(v.z); o.w = f2bf(v.w);
    reinterpret_cast<ushort4*>(out)[i] = o;
}

// Build Wcat[e][m*128+d] = W[m][d][e] (m<8) / root[d][e] (m==8), bf16, both layers.
__global__ __launch_bounds__(256) void cvt_w_k(const float* __restrict__ W1,
                                               const float* __restrict__ r1,
                                               const float* __restrict__ W2,
                                               const float* __restrict__ r2,
                                               unsigned short* __restrict__ wc1,
                                               unsigned short* __restrict__ wc2) {
    int idx = blockIdx.x * 256 + threadIdx.x;       // 0 .. 2*128*1152-1
    int l   = idx / (DD * KCAT);
    int rem = idx % (DD * KCAT);
    int e   = rem / KCAT;
    int md  = rem % KCAT;
    int m = md / DD, d = md % DD;
    const float* W = (l == 0) ? W1 : W2;
    const float* rt = (l == 0) ? r1 : r2;
    float v = (m < 8) ? W[(size_t)m * DD * DD + (size_t)d * DD + e]
                      : rt[(size_t)d * DD + e];
    ((l == 0) ? wc1 : wc2)[rem] = f2bf(v);
}

// per-(dst,r) degree + per-src out-degree (posS doubles as count)
__global__ __launch_bounds__(256) void hist_k(const int* __restrict__ src,
                                              const int* __restrict__ dst,
                                              const int* __restrict__ et,
                                              unsigned int* __restrict__ deg8,
                                              unsigned int* __restrict__ posS) {
    int e = blockIdx.x * 256 + threadIdx.x;
    if (e >= NE) return;
    atomicAdd(&deg8[(size_t)dst[e] * 8 + et[e]], 1u);
    atomicAdd(&posS[src[e]], 1u);
}

// Per node: dst-side (d,r)-grouped slot alloc (chunked by node half) and
// src-side offsets (in-place count -> base).
__global__ __launch_bounds__(256) void offs_k(const unsigned int* __restrict__ deg8,
                                              unsigned int* __restrict__ cnts,
                                              unsigned int* __restrict__ pos8,
                                              unsigned int* __restrict__ posS,
                                              unsigned int* __restrict__ segBeg,
                                              unsigned int* __restrict__ segLen,
                                              unsigned int CAP, int nch) {
    int node = blockIdx.x * 256 + threadIdx.x;
    if (node >= NN) return;
    const uint4* dp = reinterpret_cast<const uint4*>(&deg8[(size_t)node * 8]);
    uint4 a = dp[0], b = dp[1];
    unsigned int tot = a.x + a.y + a.z + a.w + b.x + b.y + b.z + b.w;
    int c = (nch == 2 && node >= NN / 2) ? 1 : 0;
    unsigned int base = atomicAdd(&cnts[c], tot) + (unsigned int)c * CAP;
    unsigned int* pp = &pos8[(size_t)node * 8];
    unsigned int run = base;
    pp[0] = run; run += a.x;  pp[1] = run; run += a.y;
    pp[2] = run; run += a.z;  pp[3] = run; run += a.w;
    pp[4] = run; run += b.x;  pp[5] = run; run += b.y;
    pp[6] = run; run += b.z;  pp[7] = run; run += b.w;
    segBeg[node] = base;
    segLen[node] = tot;
    // src side: count -> base
    unsigned int q0 = atomicAdd(&cnts[2], posS[node]);
    posS[node] = q0;
}

// Per edge: assign dst-slot p ((d,r)-grouped) and src-sorted position q.
// recD[p] = r; recA[q] = src | deg<<17; recB[q] = p.
__global__ __launch_bounds__(256) void fill_k(const int* __restrict__ src,
                                              const int* __restrict__ dst,
                                              const int* __restrict__ et,
                                              const unsigned int* __restrict__ deg8,
                                              unsigned int* __restrict__ pos8,
                                              unsigned int* __restrict__ posS,
                                              unsigned int* __restrict__ recA,
                                              unsigned int* __restrict__ recB,
                                              unsigned char* __restrict__ recD) {
    int e = blockIdx.x * 256 + threadIdx.x;
    if (e >= NE) return;
    int s = src[e], d = dst[e], r = et[e];
    unsigned int p = atomicAdd(&pos8[(size_t)d * 8 + r], 1u);
    recD[p] = (unsigned char)r;
    unsigned int q = atomicAdd(&posS[s], 1u);
    unsigned int dg = deg8[(size_t)d * 8 + r];
    if (dg > 2047u) dg = 2047u;
    recA[q] = (unsigned int)s | (dg << 17);
    recB[q] = p;
}

// Spread: walk edges in src-sorted order (x-row L1 reuse), pre-scale by
// rcp(deg), write 256B row to its dst-sorted slot (non-temporal).
// 625 blocks x 512 thr = 5000 waves x 200 edges (exact).
__global__ __launch_bounds__(512) void spread_k(const unsigned short* __restrict__ xb,
                                                const unsigned int* __restrict__ recA,
                                                const unsigned int* __restrict__ recB,
                                                unsigned short* __restrict__ y,
                                                unsigned int chunkOff, unsigned int CAP) {
    const int gw   = blockIdx.x * 8 + (threadIdx.x >> 6);   // 0..4999
    const int lane = threadIdx.x & 63;
    const int b0   = gw * 200;

    for (int b = 0; b < 200; b += 8) {
        int j = b0 + b;                                     // multiple of 8
        uint4 a0 = *reinterpret_cast<const uint4*>(recA + j);
        uint4 a1 = *reinterpret_cast<const uint4*>(recA + j + 4);
        uint4 s0 = *reinterpret_cast<const uint4*>(recB + j);
        uint4 s1 = *reinterpret_cast<const uint4*>(recB + j + 4);
        unsigned int pk[8] = {a0.x, a0.y, a0.z, a0.w, a1.x, a1.y, a1.z, a1.w};
        unsigned int sl[8] = {s0.x, s0.y, s0.z, s0.w, s1.x, s1.y, s1.z, s1.w};
        unsigned int hv[8];
#pragma unroll
        for (int u = 0; u < 8; ++u) {
            unsigned int rel = sl[u] - chunkOff;
            if (rel < CAP)
                hv[u] = *reinterpret_cast<const unsigned int*>(
                    xb + (size_t)(pk[u] & 0x1FFFFu) * DD + lane * 2);
        }
#pragma unroll
        for (int u = 0; u < 8; ++u) {
            unsigned int rel = sl[u] - chunkOff;
            if (rel < CAP) {
                float sc = __builtin_amdgcn_rcpf((float)(pk[u] >> 17));
                union { unsigned int u32; float f; } lo, hi;
                lo.u32 = hv[u] << 16; hi.u32 = hv[u] & 0xffff0000u;
                float flo = lo.f * sc, fhi = hi.f * sc;
                unsigned int w32;
                asm volatile("v_cvt_pk_bf16_f32 %0, %1, %2"
                             : "=v"(w32) : "v"(flo), "v"(fhi));
                __builtin_nontemporal_store(w32,
                    reinterpret_cast<unsigned int*>(y + (size_t)rel * DD + lane * 2));
            }
        }
    }
}

// Aggregate layer: block = 512 thr = 8 waves = 16 dst nodes (2/wave).
// Phase 1: sequential y-segment read, run-flush per relation (sum; scale was
//          pre-applied) into swizzled bf16 LDS; root x at slice 8.
// Phase 2: out[16][128] = xagg @ Wcat^T via MFMA, +bias, relu.
// mode 1: bf16 store (next layer input); mode 2: f32 store (final output).
__global__ __launch_bounds__(512) void agg_k(const unsigned short* __restrict__ xb,
                                             const unsigned short* __restrict__ wcat,
                                             const float* __restrict__ bias,
                                             const unsigned char* __restrict__ recD,
                                             const unsigned int* __restrict__ segBeg,
                                             const unsigned int* __restrict__ segLen,
                                             const unsigned short* __restrict__ y,
                                             unsigned int chunkOff, int nodeLo,
                                             unsigned short* __restrict__ obf,
                                             float* __restrict__ of32,
                                             int mode) {
    __shared__ unsigned short ldsx[16 * KCAT];      // 36,864 B
    const int wave = threadIdx.x >> 6;              // 0..7
    const int lane = threadIdx.x & 63;
    const int c16  = lane & 15;
    const int grp  = lane >> 4;
    const int lq   = lane >> 2;
    const int lm   = lane & 3;
    const int blk  = blockIdx.x;
    unsigned int* lds32 = reinterpret_cast<unsigned int*>(ldsx);

    // ---------- phase 1: sequential segment read + run-flush ----------
    for (int nl = 0; nl < 2; ++nl) {
        const int row  = wave * 2 + nl;             // LDS row 0..15
        const int node = nodeLo + blk * 16 + row;
        const int sbase = row * (KCAT / 2);         // u32 units per row
        const int xorv = row & 7;

        // zero relation slices; write root slice (m=8)
#pragma unroll
        for (int r = 0; r < 8; ++r)
            lds32[sbase + (((r * 16 + lq) ^ xorv) << 2) + lm] = 0u;
        lds32[sbase + (((128 + lq) ^ xorv) << 2) + lm] =
            *reinterpret_cast<const unsigned int*>(xb + (size_t)node * DD + lane * 2);

        const unsigned int beg = segBeg[node];
        const unsigned int len = segLen[node];
        const unsigned char* rp = recD + beg;
        const unsigned short* yb = y + (size_t)(beg - chunkOff) * DD;

        float ax = 0.f, ay = 0.f;
        unsigned int rc = 15u;
        for (unsigned int j = 0; j < len; j += 8) {
            int n = (int)(len - j); if (n > 8) n = 8;
            unsigned int hv[8]; unsigned char rr[8];
#pragma unroll
            for (int u = 0; u < 8; ++u)
                if (u < n) {
                    rr[u] = rp[j + u];
                    hv[u] = *reinterpret_cast<const unsigned int*>(
                        yb + (size_t)(j + u) * DD + lane * 2);
                }
#pragma unroll
            for (int u = 0; u < 8; ++u)
                if (u < n) {
                    unsigned int r = rr[u];
                    if (r != rc) {
                        if (rc < 8u) {
                            unsigned int w32 = ((unsigned int)f2bf(ay) << 16)
                                             | (unsigned int)f2bf(ax);
                            lds32[sbase + ((((int)rc * 16 + lq) ^ xorv) << 2) + lm] = w32;
                        }
                        rc = r; ax = 0.f; ay = 0.f;
                    }
                    union { unsigned int u32; float f; } lo, hi;
                    lo.u32 = hv[u] << 16; hi.u32 = hv[u] & 0xffff0000u;
                    ax += lo.f; ay += hi.f;
                }
        }
        if (rc < 8u) {
            unsigned int w32 = ((unsigned int)f2bf(ay) << 16)
                             | (unsigned int)f2bf(ax);
            lds32[sbase + ((((int)rc * 16 + lq) ^ xorv) << 2) + lm] = w32;
        }
    }
    __syncthreads();

    // ---------- phase 2: MFMA out = xagg @ Wcat^T (wave w -> col tile w) ----------
    f32x4 acc = f32x4{0.f, 0.f, 0.f, 0.f};
    const unsigned short* arow = wcat + (size_t)(wave * 16 + c16) * KCAT;
#pragma unroll
    for (int kk = 0; kk < KCAT / 32; ++kk) {        // 36 k-steps
        int slot = (kk * 4 + grp) ^ (c16 & 7);
        bf16x8 b = *reinterpret_cast<const bf16x8*>(&ldsx[c16 * KCAT + slot * 8]);
        bf16x8 a = *reinterpret_cast<const bf16x8*>(arow + kk * 32 + grp * 8);
        acc = __builtin_amdgcn_mfma_f32_16x16x32_bf16(a, b, acc, 0, 0, 0);
    }

    // ---------- epilogue: +bias, relu, store ----------
    const int node = nodeLo + blk * 16 + c16;
    const int od = wave * 16 + grp * 4;
    const float4 bv = *reinterpret_cast<const float4*>(bias + od);
    float o0 = fmaxf(acc[0] + bv.x, 0.f);
    float o1 = fmaxf(acc[1] + bv.y, 0.f);
    float o2 = fmaxf(acc[2] + bv.z, 0.f);
    float o3 = fmaxf(acc[3] + bv.w, 0.f);
    if (mode == 1) {
        union { unsigned short s[4]; uint2 v; } pko;
        pko.s[0] = f2bf(o0); pko.s[1] = f2bf(o1);
        pko.s[2] = f2bf(o2); pko.s[3] = f2bf(o3);
        *reinterpret_cast<uint2*>(obf + (size_t)node * DD + od) = pko.v;
    } else {
        *reinterpret_cast<float4*>(of32 + (size_t)node * DD + od)
            = make_float4(o0, o1, o2, o3);
    }
}

extern "C" void kernel_launch(void* const* d_in, const int* in_sizes, int n_in,
                              void* d_out, int out_size, void* d_ws, size_t ws_size,
                              hipStream_t stream) {
    const float* x  = (const float*)d_in[0];
    const int*   ei = (const int*)d_in[1];
    const int*   et = (const int*)d_in[2];
    const float* W1 = (const float*)d_in[3];
    const float* r1 = (const float*)d_in[4];
    const float* b1 = (const float*)d_in[5];
    const float* W2 = (const float*)d_in[6];
    const float* r2 = (const float*)d_in[7];
    const float* b2 = (const float*)d_in[8];
    float* out = (float*)d_out;

    // ---- fixed workspace layout (~67.5 MB) ----
    char* ws = (char*)d_ws;
    unsigned int*   deg8   = (unsigned int*)ws;                   // NN*8 u32
    unsigned int*   cnts   = deg8 + (size_t)NN * 8;               // 64 u32
    unsigned int*   posS   = cnts + 64;                           // NN u32
    unsigned int*   pos8   = posS + NN;                           // NN*8 u32
    unsigned int*   segBeg = pos8 + (size_t)NN * 8;               // NN u32
    unsigned int*   segLen = segBeg + NN;                         // NN u32
    unsigned int*   recA   = segLen + NN;                         // NE u32
    unsigned int*   recB   = recA + NE;                           // NE u32
    unsigned short* wc1    = (unsigned short*)(recB + NE);        // 294,912 B
    unsigned short* wc2    = wc1 + DD * KCAT;
    unsigned short* xbuf   = wc2 + DD * KCAT;                     // 25.6 MB
    unsigned short* xbuf2  = xbuf + (size_t)NN * DD;              // 25.6 MB
    size_t fixedEnd = (size_t)((char*)(xbuf2 + (size_t)NN * DD) - ws);
    fixedEnd = (fixedEnd + 255) & ~(size_t)255;

    // ---- adaptive y / recD sizing ----
    if (ws_size < fixedEnd + 1024) return;
    size_t avail = ws_size - fixedEnd - 512;
    int nch; unsigned int CAP;
    if (avail >= (size_t)NE * 257) { nch = 1; CAP = NE; }
    else {
        nch = 2;
        CAP = (unsigned int)(avail / 258);
        if (CAP < 530000u) return;                  // loud failure
        if (CAP > NE) CAP = NE;
    }
    unsigned char* recD = (unsigned char*)(ws + fixedEnd);        // nch*CAP B
    size_t yOff = (fixedEnd + (size_t)nch * CAP + 255) & ~(size_t)255;
    unsigned short* y = (unsigned short*)(ws + yOff);             // CAP*256 B

    const int* srcv = ei;
    const int* dstv = ei + NE;

    hipMemsetAsync(deg8, 0, (size_t)NN * 8 * 4 + 256 + (size_t)NN * 4, stream);
    cvt_x_k<<<(NN * DD / 4) / 256, 256, 0, stream>>>(x, xbuf, NN * DD / 4);
    cvt_w_k<<<(2 * DD * KCAT) / 256, 256, 0, stream>>>(W1, r1, W2, r2, wc1, wc2);
    hist_k<<<(NE + 255) / 256, 256, 0, stream>>>(srcv, dstv, et, deg8, posS);
    offs_k<<<(NN + 255) / 256, 256, 0, stream>>>(deg8, cnts, pos8, posS,
                                                 segBeg, segLen, CAP, nch);
    fill_k<<<(NE + 255) / 256, 256, 0, stream>>>(srcv, dstv, et, deg8, pos8, posS,
                                                 recA, recB, recD);

    const int nodesPer = NN / nch;                  // 100000 or 50000
    const int aggBlocks = nodesPer / 16;            // 6250 or 3125
    for (int layer = 0; layer < 2; ++layer) {
        const unsigned short* in = layer ? xbuf2 : xbuf;
        const unsigned short* wc = layer ? wc2 : wc1;
        const float* bb = layer ? b2 : b1;
        for (int c = 0; c < nch; ++c) {
            unsigned int chunkOff = (unsigned int)c * CAP;
            spread_k<<<625, 512, 0, stream>>>(in, recA, recB, y, chunkOff, CAP);
            agg_k<<<aggBlocks, 512, 0, stream>>>(in, wc, bb, recD, segBeg, segLen,
                                                 y, chunkOff, c * nodesPer,
                                                 layer ? (unsigned short*)nullptr : xbuf2,
                                                 layer ? out : (float*)nullptr,
                                                 layer ? 2 : 1);
        }
    }
}